// Round 7
// baseline (176.492 us; speedup 1.0000x reference)
//
#include <hip/hip_runtime.h>
#include <hip/hip_bf16.h>
#include <math.h>

#define BB 2
#define TT 2048
#define CCH 1024
#define HH 16
#define DD 64
#define BT (BB*TT)     // 4096
#define N3 (3*CCH)     // 3072
#define NJOBS 40       // sum over 16 q-tiles of ceil((qt+1)/4)

typedef __attribute__((ext_vector_type(8))) short short8;
typedef __attribute__((ext_vector_type(4))) float f32x4;
typedef __attribute__((ext_vector_type(16))) float f32x16;

__device__ __forceinline__ unsigned short f2bf(float f) {
  unsigned int u = __float_as_uint(f);
  unsigned int r = (u + 0x7FFFu + ((u >> 16) & 1u)) >> 16;  // RNE
  return (unsigned short)r;
}
__device__ __forceinline__ float bf2f(unsigned short u) {
  return __uint_as_float(((unsigned int)u) << 16);
}
__device__ __forceinline__ int cvtpk(float lo, float hi) {
  int r;
  asm("v_cvt_pk_bf16_f32 %0, %1, %2" : "=v"(r) : "v"(lo), "v"(hi));
  return r;
}
__device__ __forceinline__ void plswap(int &a, int &b) {
  asm("v_permlane32_swap_b32 %0, %1" : "+v"(a), "+v"(b));
}
__device__ __forceinline__ float fexp2(float x) {   // native v_exp_f32: 2^x, 1 inst
  float r;
  asm("v_exp_f32 %0, %1" : "=v"(r) : "v"(x));
  return r;
}
__device__ __forceinline__ void gload_lds16(const unsigned short* g, unsigned short* l) {
  __builtin_amdgcn_global_load_lds((const __attribute__((address_space(1))) void*)g,
                                   (__attribute__((address_space(3))) void*)l, 16, 0, 0);
}
__device__ __forceinline__ float fmax3(float a, float b, float c) {
  return fmaxf(fmaxf(a, b), c);   // fuses to v_max3_f32
}
// job-base for q-tile qt
__device__ __forceinline__ int jbase(int qt) {
  int a = qt >> 2, b = qt & 3;
  return qt + 2 * a * (a - 1) + a * b;
}

// ---------------- f32 -> bf16 flat convert ----------------
__global__ __launch_bounds__(256) void k_convert(const float* __restrict__ in,
                                                 unsigned short* __restrict__ out, int n8) {
  int i = blockIdx.x * 256 + threadIdx.x;
  if (i < n8) {
    const float4 a = *(const float4*)(in + (size_t)i * 8);
    const float4 b = *(const float4*)(in + (size_t)i * 8 + 4);
    short8 v;
    v[0] = f2bf(a.x); v[1] = f2bf(a.y); v[2] = f2bf(a.z); v[3] = f2bf(a.w);
    v[4] = f2bf(b.x); v[5] = f2bf(b.y); v[6] = f2bf(b.z); v[7] = f2bf(b.w);
    *(short8*)(out + (size_t)i * 8) = v;
  }
}

// ---------------- transpose + f32->bf16 convert: out[c][r] = in[r][c] ----------------
__global__ __launch_bounds__(256) void k_transpose_cvt(const float* __restrict__ in,
                                                       unsigned short* __restrict__ out,
                                                       int R, int Cn) {
  __shared__ float tile[32][33];
  int tc = blockIdx.x * 32;
  int tr = blockIdx.y * 32;
  int lx = threadIdx.x & 31;
  int ly = threadIdx.x >> 5;  // 0..7
#pragma unroll
  for (int i = 0; i < 32; i += 8)
    tile[ly + i][lx] = in[(size_t)(tr + ly + i) * Cn + tc + lx];
  __syncthreads();
#pragma unroll
  for (int i = 0; i < 32; i += 8)
    out[(size_t)(tc + ly + i) * R + tr + lx] = f2bf(tile[lx][ly + i]);
}

// ---------------- QKV GEMM (m97 pattern): Xb bf16 @ Wt bf16 -> Q(scaled),K,Vt bf16 ----------------
__global__ __launch_bounds__(256) void k_qkv_gemm(const unsigned short* __restrict__ Xb,
                                                  const unsigned short* __restrict__ Wt,
                                                  const float* __restrict__ bias,
                                                  unsigned short* __restrict__ Qo,
                                                  unsigned short* __restrict__ Ko,
                                                  unsigned short* __restrict__ Vto) {
  __shared__ __align__(16) unsigned short As[128 * 32];
  __shared__ __align__(16) unsigned short Bs[128 * 32];
  int tid = threadIdx.x;
  int mb = blockIdx.x * 128;
  int nb = blockIdx.y * 128;
  int wid = tid >> 6, lane = tid & 63;
  int wr = (wid >> 1) * 64, wc = (wid & 1) * 64;
  int l15 = lane & 15, l4 = lane >> 4;
  int l16 = lane >> 2, lc = (lane & 3) * 8;   // staging row-within-16 / col
  f32x4 acc[4][4];
#pragma unroll
  for (int a = 0; a < 4; ++a)
#pragma unroll
    for (int b = 0; b < 4; ++b)
#pragma unroll
      for (int j = 0; j < 4; ++j) acc[a][b][j] = 0.0f;

  for (int kb = 0; kb < CCH; kb += 32) {
#pragma unroll
    for (int i = 0; i < 2; ++i) {
      int arow = wid * 32 + i * 16;
      gload_lds16(Xb + (size_t)(mb + arow + l16) * CCH + kb + lc, &As[arow * 32]);
      gload_lds16(Wt + (size_t)(nb + arow + l16) * CCH + kb + lc, &Bs[arow * 32]);
    }
    __syncthreads();
    short8 af[4], bfr[4];
#pragma unroll
    for (int mt = 0; mt < 4; ++mt) af[mt] = *(const short8*)(&As[(wr + mt * 16 + l15) * 32 + l4 * 8]);
#pragma unroll
    for (int nt = 0; nt < 4; ++nt) bfr[nt] = *(const short8*)(&Bs[(wc + nt * 16 + l15) * 32 + l4 * 8]);
#pragma unroll
    for (int mt = 0; mt < 4; ++mt)
#pragma unroll
      for (int nt = 0; nt < 4; ++nt)
        acc[mt][nt] = __builtin_amdgcn_mfma_f32_16x16x32_bf16(af[mt], bfr[nt], acc[mt][nt], 0, 0, 0);
    __syncthreads();
  }

#pragma unroll
  for (int mt = 0; mt < 4; ++mt) {
#pragma unroll
    for (int nt = 0; nt < 4; ++nt) {
      int gcol = nb + wc + nt * 16 + l15;        // 0..3071
      int which = gcol >> 10;
      int cc = gcol & 1023;
      int h = cc >> 6, d = cc & 63;
      float bv = bias[gcol];
#pragma unroll
      for (int j = 0; j < 4; ++j) {
        int grow = mb + wr + mt * 16 + l4 * 4 + j;  // 0..4095
        int b = grow >> 11, t = grow & 2047;
        float v = acc[mt][nt][j] + bv;
        size_t bh = (size_t)(b * HH + h);
        // fold sm_scale AND log2(e): softmax runs in exp2 domain
        if (which == 0)      Qo[(bh * TT + t) * DD + d] = f2bf(v * 0.18033688f);
        else if (which == 1) Ko[(bh * TT + t) * DD + d] = f2bf(v);
        else                 Vto[(bh * DD + d) * TT + t] = f2bf(v);
      }
    }
  }
}

// ---------------- causal flash attention: LDS-free, direct global MFMA operands ----------------
// K/V are L2-resident (512KB per bh); fragments load straight from global.
// No barriers -> waves fully decoupled; non-working waves break out early.
__global__ __launch_bounds__(256) void k_attn(const unsigned short* __restrict__ Qb,
                                              const unsigned short* __restrict__ Kb,
                                              const unsigned short* __restrict__ Vtb,
                                              unsigned short* __restrict__ PO,
                                              float* __restrict__ Pm,
                                              float* __restrict__ Pl) {
  int tid = threadIdx.x;
  int jx = blockIdx.x;
  int bh = blockIdx.y;
  int qt = 0;
#pragma unroll
  for (int q = 1; q < 16; ++q)
    if (jx >= jbase(q)) qt = q;
  int chunk = jx - jbase(qt);
  int t0 = chunk * 8;
  int t1 = min(t0 + 8, (qt + 1) * 2);
  size_t job = (size_t)bh * NJOBS + jx;

  const unsigned short* Qp = Qb + (size_t)bh * TT * DD;
  const unsigned short* Kp = Kb + (size_t)bh * TT * DD;
  const unsigned short* Vp = Vtb + (size_t)bh * DD * TT;
  int wid = tid >> 6, lane = tid & 63;
  int l31 = lane & 31, h = lane >> 5;
  int q0 = qt * 128 + wid * 32;
  int qrow = q0 + l31;

  short8 qf[4];
#pragma unroll
  for (int m = 0; m < 4; ++m)
    qf[m] = *(const short8*)(Qp + (size_t)qrow * DD + m * 16 + h * 8);

  // persistent zero vector: C-operand for first QK MFMA
  f32x16 zv;
#pragma unroll
  for (int r = 0; r < 16; ++r) zv[r] = 0.0f;

  f32x16 po[2];
  po[0] = zv; po[1] = zv;
  float mrun = -1e30f, lrun = 0.0f;

  for (int t = t0; t < t1; ++t) {
    int kvb = t * 64;
    if (kvb > q0 + 31) break;        // tiles ascend; nothing left for this wave

    // S^T = K · Q^T, K-fragments straight from global (L1/L2-served)
    f32x16 st[2];
    __builtin_amdgcn_s_setprio(1);
#pragma unroll
    for (int t32 = 0; t32 < 2; ++t32) {
      const unsigned short* kbase = Kp + (size_t)(kvb + t32 * 32 + l31) * DD + h * 8;
      st[t32] = __builtin_amdgcn_mfma_f32_32x32x16_bf16(*(const short8*)kbase, qf[0], zv, 0, 0, 0);
#pragma unroll
      for (int m = 1; m < 4; ++m)
        st[t32] = __builtin_amdgcn_mfma_f32_32x32x16_bf16(*(const short8*)(kbase + m * 16), qf[m],
                                                          st[t32], 0, 0, 0);
    }
    __builtin_amdgcn_s_setprio(0);

    if (kvb + 63 > q0) {             // diagonal tiles: causal mask
#pragma unroll
      for (int t32 = 0; t32 < 2; ++t32)
#pragma unroll
        for (int r = 0; r < 16; ++r) {
          int kvg = kvb + t32 * 32 + (r & 3) + 8 * (r >> 2) + 4 * h;
          if (kvg > qrow) st[t32][r] = -1e30f;
        }
    }

    // row max: 4-chain v_max3 tree over 32 values, then cross-half
    float A = st[0][0], B = st[0][1], C = st[0][2], Dv = st[0][3];
#pragma unroll
    for (int r = 4; r < 16; r += 4) {
      A = fmax3(A, st[0][r], st[0][r + 1]);
      B = fmax3(B, st[0][r + 2], st[0][r + 3]);
      C = fmax3(C, st[1][r - 4], st[1][r - 3]);
      Dv = fmax3(Dv, st[1][r - 2], st[1][r - 1]);
    }
    C = fmax3(C, st[1][12], st[1][13]);
    Dv = fmax3(Dv, st[1][14], st[1][15]);
    float mx = fmaxf(fmax3(A, B, C), Dv);
    mx = fmaxf(mx, __shfl_xor(mx, 32));

    if (__any(mx - mrun > 8.0f)) {   // defer-max, log2 units
      float mnew = fmaxf(mrun, mx);
      float alpha = fexp2(mrun - mnew);
      lrun *= alpha;
#pragma unroll
      for (int dt = 0; dt < 2; ++dt)
#pragma unroll
        for (int r = 0; r < 16; ++r) po[dt][r] *= alpha;
      mrun = mnew;
    }

    float sum = 0.0f;
#pragma unroll
    for (int t32 = 0; t32 < 2; ++t32)
#pragma unroll
      for (int r = 0; r < 16; ++r) {
        float p = fexp2(st[t32][r] - mrun);
        st[t32][r] = p;
        sum += p;
      }
    sum += __shfl_xor(sum, 32);
    lrun += sum;

    // P -> bf16 B-fragments via cvt_pk + permlane32_swap
    short8 pf[4];
#pragma unroll
    for (int g = 0; g < 4; ++g) {
      int t32 = g >> 1, r0 = (g & 1) * 8;
      int a = cvtpk(st[t32][r0 + 0], st[t32][r0 + 1]);
      int b = cvtpk(st[t32][r0 + 4], st[t32][r0 + 5]);
      plswap(a, b);
      int c = cvtpk(st[t32][r0 + 2], st[t32][r0 + 3]);
      int d = cvtpk(st[t32][r0 + 6], st[t32][r0 + 7]);
      plswap(c, d);
      union { int w[4]; short8 s; } u;
      u.w[0] = a; u.w[1] = c; u.w[2] = b; u.w[3] = d;
      pf[g] = u.s;
    }

    // O^T += V^T · P, V^T-fragments straight from global
    __builtin_amdgcn_s_setprio(1);
#pragma unroll
    for (int dt = 0; dt < 2; ++dt) {
      const unsigned short* vbase = Vp + (size_t)(dt * 32 + l31) * TT + kvb + h * 8;
#pragma unroll
      for (int g = 0; g < 4; ++g)
        po[dt] = __builtin_amdgcn_mfma_f32_32x32x16_bf16(*(const short8*)(vbase + g * 16), pf[g],
                                                         po[dt], 0, 0, 0);
    }
    __builtin_amdgcn_s_setprio(0);
  }

  int wrow = wid * 32 + l31;
  size_t pobase = (job * 128 + wrow) * 64;
#pragma unroll
  for (int dt = 0; dt < 2; ++dt)
#pragma unroll
    for (int r = 0; r < 16; r += 2) {
      int d = dt * 32 + (r & 3) + 8 * (r >> 2) + 4 * h;
      int w = cvtpk(po[dt][r], po[dt][r + 1]);
      *(int*)(PO + pobase + d) = w;
    }
  if (h == 0) {
    Pm[job * 128 + wrow] = mrun;
    Pl[job * 128 + wrow] = lrun;
  }
}

// ---------------- combine partials -> Yb bf16 (exp2 domain) ----------------
__global__ __launch_bounds__(256) void k_attn_combine(const unsigned short* __restrict__ PO,
                                                      const float* __restrict__ Pm,
                                                      const float* __restrict__ Pl,
                                                      unsigned short* __restrict__ Y) {
  int qt = blockIdx.x, bh = blockIdx.y;
  int nc = (qt >> 2) + 1;
  size_t job0 = (size_t)bh * NJOBS + jbase(qt);
  int tid = threadIdx.x;
  int row = tid >> 1, half = tid & 1;

  float m[4], l[4];
  float M = -1e30f;
  for (int c = 0; c < nc; ++c) {
    m[c] = Pm[(job0 + c) * 128 + row];
    l[c] = Pl[(job0 + c) * 128 + row];
    M = fmaxf(M, m[c]);
  }
  float L = 0.0f, w[4];
  for (int c = 0; c < nc; ++c) {
    w[c] = fexp2(m[c] - M);
    L += l[c] * w[c];
  }
  float inv = 1.0f / L;

  float acc[32];
#pragma unroll
  for (int j = 0; j < 32; ++j) acc[j] = 0.0f;
  for (int c = 0; c < nc; ++c) {
    const unsigned short* p = PO + ((job0 + c) * 128 + row) * 64 + half * 32;
    float wc = w[c];
#pragma unroll
    for (int k = 0; k < 4; ++k) {
      short8 v = *(const short8*)(p + k * 8);
#pragma unroll
      for (int j = 0; j < 8; ++j) acc[k * 8 + j] += wc * bf2f((unsigned short)v[j]);
    }
  }
  int b = bh >> 4, hh = bh & 15;
  int t = qt * 128 + row;
  unsigned short* yp = Y + ((size_t)(b * TT + t)) * CCH + hh * DD + half * 32;
#pragma unroll
  for (int k = 0; k < 4; ++k) {
    short8 wv;
#pragma unroll
    for (int j = 0; j < 8; ++j) wv[j] = (short)f2bf(acc[k * 8 + j] * inv);
    *(short8*)(yp + k * 8) = wv;
  }
}

// ---------------- proj GEMM (m97 pattern): Yb bf16 @ Wt_proj bf16 + bias -> f32 out ----------------
__global__ __launch_bounds__(256) void k_proj_gemm(const unsigned short* __restrict__ Yb,
                                                   const unsigned short* __restrict__ Wt,
                                                   const float* __restrict__ bias,
                                                   float* __restrict__ Out) {
  __shared__ __align__(16) unsigned short As[128 * 32];
  __shared__ __align__(16) unsigned short Bs[128 * 32];
  int tid = threadIdx.x;
  int mb = blockIdx.x * 128;
  int nb = blockIdx.y * 128;
  int wid = tid >> 6, lane = tid & 63;
  int wr = (wid >> 1) * 64, wc = (wid & 1) * 64;
  int l15 = lane & 15, l4 = lane >> 4;
  int l16 = lane >> 2, lc = (lane & 3) * 8;
  f32x4 acc[4][4];
#pragma unroll
  for (int a = 0; a < 4; ++a)
#pragma unroll
    for (int b = 0; b < 4; ++b)
#pragma unroll
      for (int j = 0; j < 4; ++j) acc[a][b][j] = 0.0f;

  for (int kb = 0; kb < CCH; kb += 32) {
#pragma unroll
    for (int i = 0; i < 2; ++i) {
      int arow = wid * 32 + i * 16;
      gload_lds16(Yb + (size_t)(mb + arow + l16) * CCH + kb + lc, &As[arow * 32]);
      gload_lds16(Wt + (size_t)(nb + arow + l16) * CCH + kb + lc, &Bs[arow * 32]);
    }
    __syncthreads();
    short8 af[4], bfr[4];
#pragma unroll
    for (int mt = 0; mt < 4; ++mt) af[mt] = *(const short8*)(&As[(wr + mt * 16 + l15) * 32 + l4 * 8]);
#pragma unroll
    for (int nt = 0; nt < 4; ++nt) bfr[nt] = *(const short8*)(&Bs[(wc + nt * 16 + l15) * 32 + l4 * 8]);
#pragma unroll
    for (int mt = 0; mt < 4; ++mt)
#pragma unroll
      for (int nt = 0; nt < 4; ++nt)
        acc[mt][nt] = __builtin_amdgcn_mfma_f32_16x16x32_bf16(af[mt], bfr[nt], acc[mt][nt], 0, 0, 0);
    __syncthreads();
  }

#pragma unroll
  for (int mt = 0; mt < 4; ++mt) {
#pragma unroll
    for (int nt = 0; nt < 4; ++nt) {
      int gcol = nb + wc + nt * 16 + l15;
      float bv = bias[gcol];
#pragma unroll
      for (int j = 0; j < 4; ++j) {
        int grow = mb + wr + mt * 16 + l4 * 4 + j;
        Out[(size_t)grow * CCH + gcol] = acc[mt][nt][j] + bv;
      }
    }
  }
}

extern "C" void kernel_launch(void* const* d_in, const int* in_sizes, int n_in,
                              void* d_out, int out_size, void* d_ws, size_t ws_size,
                              hipStream_t stream) {
  const float* x      = (const float*)d_in[0];
  const float* W_qkv  = (const float*)d_in[1];
  const float* b_qkv  = (const float*)d_in[2];
  const float* W_proj = (const float*)d_in[3];
  const float* b_proj = (const float*)d_in[4];
  float* out = (float*)d_out;

  char* ws = (char*)d_ws;
  size_t off = 0;
  unsigned short* Wt_qkv  = (unsigned short*)(ws + off); off += (size_t)N3 * CCH * 2;   // 6.3 MB
  unsigned short* Wt_proj = (unsigned short*)(ws + off); off += (size_t)CCH * CCH * 2;  // 2.1 MB
  unsigned short* Xb      = (unsigned short*)(ws + off); off += (size_t)BT * CCH * 2;   // 8.4 MB
  unsigned short* Qb      = (unsigned short*)(ws + off); off += (size_t)BT * CCH * 2;   // 8.4 MB
  unsigned short* Kb      = (unsigned short*)(ws + off); off += (size_t)BT * CCH * 2;   // 8.4 MB
  unsigned short* Vt      = (unsigned short*)(ws + off); off += (size_t)BT * CCH * 2;   // 8.4 MB
  unsigned short* Yb      = (unsigned short*)(ws + off); off += (size_t)BT * CCH * 2;   // 8.4 MB
  unsigned short* PO      = (unsigned short*)(ws + off); off += (size_t)32 * NJOBS * 128 * 64 * 2; // 21 MB
  float*          Pm      = (float*)(ws + off);          off += (size_t)32 * NJOBS * 128 * 4;
  float*          Pl      = (float*)(ws + off);          off += (size_t)32 * NJOBS * 128 * 4;

  k_convert<<<dim3(BT * CCH / 8 / 256), 256, 0, stream>>>(x, Xb, BT * CCH / 8);
  k_transpose_cvt<<<dim3(N3 / 32, CCH / 32), 256, 0, stream>>>(W_qkv, Wt_qkv, CCH, N3);
  k_transpose_cvt<<<dim3(CCH / 32, CCH / 32), 256, 0, stream>>>(W_proj, Wt_proj, CCH, CCH);
  k_qkv_gemm<<<dim3(BT / 128, N3 / 128), 256, 0, stream>>>(Xb, Wt_qkv, b_qkv, Qb, Kb, Vt);
  k_attn<<<dim3(NJOBS, BB * HH), 256, 0, stream>>>(Qb, Kb, Vt, PO, Pm, Pl);
  k_attn_combine<<<dim3(TT / 128, BB * HH), 256, 0, stream>>>(PO, Pm, Pl, Yb);
  k_proj_gemm<<<dim3(BT / 128, CCH / 128), 256, 0, stream>>>(Yb, Wt_proj, b_proj, out);
}

// Round 8
// 131.952 us; speedup vs baseline: 1.3376x; 1.3376x over previous
//
#include <hip/hip_runtime.h>
#include <hip/hip_bf16.h>
#include <math.h>

#define BB 2
#define TT 2048
#define CCH 1024
#define HH 16
#define DD 64
#define BT (BB*TT)     // 4096
#define N3 (3*CCH)     // 3072
#define NJOBS 61       // sum over 16 q-tiles of ceil(2(qt+1)/5)  (5-tile chunks)

typedef __attribute__((ext_vector_type(8))) short short8;
typedef __attribute__((ext_vector_type(4))) float f32x4;
typedef __attribute__((ext_vector_type(16))) float f32x16;

__device__ __forceinline__ unsigned short f2bf(float f) {
  unsigned int u = __float_as_uint(f);
  unsigned int r = (u + 0x7FFFu + ((u >> 16) & 1u)) >> 16;  // RNE
  return (unsigned short)r;
}
__device__ __forceinline__ float bf2f(unsigned short u) {
  return __uint_as_float(((unsigned int)u) << 16);
}
__device__ __forceinline__ int cvtpk(float lo, float hi) {
  int r;
  asm("v_cvt_pk_bf16_f32 %0, %1, %2" : "=v"(r) : "v"(lo), "v"(hi));
  return r;
}
__device__ __forceinline__ void plswap(int &a, int &b) {
  asm("v_permlane32_swap_b32 %0, %1" : "+v"(a), "+v"(b));
}
__device__ __forceinline__ float fexp2(float x) {   // native v_exp_f32: 2^x, 1 inst
  float r;
  asm("v_exp_f32 %0, %1" : "=v"(r) : "v"(x));
  return r;
}
__device__ __forceinline__ void gload_lds16(const unsigned short* g, unsigned short* l) {
  __builtin_amdgcn_global_load_lds((const __attribute__((address_space(1))) void*)g,
                                   (__attribute__((address_space(3))) void*)l, 16, 0, 0);
}
__device__ __forceinline__ float fmax3(float a, float b, float c) {
  return fmaxf(fmaxf(a, b), c);   // fuses to v_max3_f32
}
// job-base for q-tile qt (5-tile chunks): sum_{q<qt} ceil(2(q+1)/5)
__device__ __forceinline__ int jbase(int qt) {
  int s = 0;
#pragma unroll
  for (int q = 0; q < 16; ++q)
    if (q < qt) s += (2 * q + 6) / 5;
  return s;
}

// ---------------- f32 -> bf16 flat convert ----------------
__global__ __launch_bounds__(256) void k_convert(const float* __restrict__ in,
                                                 unsigned short* __restrict__ out, int n8) {
  int i = blockIdx.x * 256 + threadIdx.x;
  if (i < n8) {
    const float4 a = *(const float4*)(in + (size_t)i * 8);
    const float4 b = *(const float4*)(in + (size_t)i * 8 + 4);
    short8 v;
    v[0] = f2bf(a.x); v[1] = f2bf(a.y); v[2] = f2bf(a.z); v[3] = f2bf(a.w);
    v[4] = f2bf(b.x); v[5] = f2bf(b.y); v[6] = f2bf(b.z); v[7] = f2bf(b.w);
    *(short8*)(out + (size_t)i * 8) = v;
  }
}

// ---------------- transpose + f32->bf16 convert: out[c][r] = in[r][c] ----------------
__global__ __launch_bounds__(256) void k_transpose_cvt(const float* __restrict__ in,
                                                       unsigned short* __restrict__ out,
                                                       int R, int Cn) {
  __shared__ float tile[32][33];
  int tc = blockIdx.x * 32;
  int tr = blockIdx.y * 32;
  int lx = threadIdx.x & 31;
  int ly = threadIdx.x >> 5;  // 0..7
#pragma unroll
  for (int i = 0; i < 32; i += 8)
    tile[ly + i][lx] = in[(size_t)(tr + ly + i) * Cn + tc + lx];
  __syncthreads();
#pragma unroll
  for (int i = 0; i < 32; i += 8)
    out[(size_t)(tc + ly + i) * R + tr + lx] = f2bf(tile[lx][ly + i]);
}

// ---------------- QKV GEMM (m97 pattern): Xb bf16 @ Wt bf16 -> Q(scaled),K,Vt bf16 ----------------
__global__ __launch_bounds__(256) void k_qkv_gemm(const unsigned short* __restrict__ Xb,
                                                  const unsigned short* __restrict__ Wt,
                                                  const float* __restrict__ bias,
                                                  unsigned short* __restrict__ Qo,
                                                  unsigned short* __restrict__ Ko,
                                                  unsigned short* __restrict__ Vto) {
  __shared__ __align__(16) unsigned short As[128 * 32];
  __shared__ __align__(16) unsigned short Bs[128 * 32];
  int tid = threadIdx.x;
  int mb = blockIdx.x * 128;
  int nb = blockIdx.y * 128;
  int wid = tid >> 6, lane = tid & 63;
  int wr = (wid >> 1) * 64, wc = (wid & 1) * 64;
  int l15 = lane & 15, l4 = lane >> 4;
  int l16 = lane >> 2, lc = (lane & 3) * 8;   // staging row-within-16 / col
  f32x4 acc[4][4];
#pragma unroll
  for (int a = 0; a < 4; ++a)
#pragma unroll
    for (int b = 0; b < 4; ++b)
#pragma unroll
      for (int j = 0; j < 4; ++j) acc[a][b][j] = 0.0f;

  for (int kb = 0; kb < CCH; kb += 32) {
#pragma unroll
    for (int i = 0; i < 2; ++i) {
      int arow = wid * 32 + i * 16;
      gload_lds16(Xb + (size_t)(mb + arow + l16) * CCH + kb + lc, &As[arow * 32]);
      gload_lds16(Wt + (size_t)(nb + arow + l16) * CCH + kb + lc, &Bs[arow * 32]);
    }
    __syncthreads();
    short8 af[4], bfr[4];
#pragma unroll
    for (int mt = 0; mt < 4; ++mt) af[mt] = *(const short8*)(&As[(wr + mt * 16 + l15) * 32 + l4 * 8]);
#pragma unroll
    for (int nt = 0; nt < 4; ++nt) bfr[nt] = *(const short8*)(&Bs[(wc + nt * 16 + l15) * 32 + l4 * 8]);
#pragma unroll
    for (int mt = 0; mt < 4; ++mt)
#pragma unroll
      for (int nt = 0; nt < 4; ++nt)
        acc[mt][nt] = __builtin_amdgcn_mfma_f32_16x16x32_bf16(af[mt], bfr[nt], acc[mt][nt], 0, 0, 0);
    __syncthreads();
  }

#pragma unroll
  for (int mt = 0; mt < 4; ++mt) {
#pragma unroll
    for (int nt = 0; nt < 4; ++nt) {
      int gcol = nb + wc + nt * 16 + l15;        // 0..3071
      int which = gcol >> 10;
      int cc = gcol & 1023;
      int h = cc >> 6, d = cc & 63;
      float bv = bias[gcol];
#pragma unroll
      for (int j = 0; j < 4; ++j) {
        int grow = mb + wr + mt * 16 + l4 * 4 + j;  // 0..4095
        int b = grow >> 11, t = grow & 2047;
        float v = acc[mt][nt][j] + bv;
        size_t bh = (size_t)(b * HH + h);
        // fold sm_scale AND log2(e): softmax runs in exp2 domain
        if (which == 0)      Qo[(bh * TT + t) * DD + d] = f2bf(v * 0.18033688f);
        else if (which == 1) Ko[(bh * TT + t) * DD + d] = f2bf(v);
        else                 Vto[(bh * DD + d) * TT + t] = f2bf(v);
      }
    }
  }
}

// ---------------- causal flash attention: swapped QK^T, in-register softmax (exp2 domain) ----------------
// 5-tile KV chunks (NJOBS=61/bh): shorter jobs + backfill. K/V staged via
// global_load_lds with pre-swizzled global source (linear LDS dest, XOR-swizzled reads).
__global__ __launch_bounds__(256) void k_attn(const unsigned short* __restrict__ Qb,
                                              const unsigned short* __restrict__ Kb,
                                              const unsigned short* __restrict__ Vtb,
                                              unsigned short* __restrict__ PO,
                                              float* __restrict__ Pm,
                                              float* __restrict__ Pl) {
  __shared__ __align__(16) unsigned short Ks[2][64 * 64];   // [kv][d], XOR-swizzled 16B chunks
  __shared__ __align__(16) unsigned short Vs[2][64 * 64];   // [d][kv], XOR-swizzled 16B chunks
  int tid = threadIdx.x;
  int jx = (NJOBS - 1) - blockIdx.x;          // LPT: biggest jobs first (matters with backfill)
  int bh = blockIdx.y;
  int qt = 0;
#pragma unroll
  for (int q = 1; q < 16; ++q)
    if (jx >= jbase(q)) qt = q;
  int chunk = jx - jbase(qt);
  int t0 = chunk * 5;
  int t1 = min(t0 + 5, (qt + 1) * 2);
  size_t job = (size_t)bh * NJOBS + jx;

  const unsigned short* Qp = Qb + (size_t)bh * TT * DD;
  const unsigned short* Kp = Kb + (size_t)bh * TT * DD;
  const unsigned short* Vp = Vtb + (size_t)bh * DD * TT;
  int wid = tid >> 6, lane = tid & 63;
  int l31 = lane & 31, h = lane >> 5;
  int q0 = qt * 128 + wid * 32;
  int qrow = q0 + l31;

  // per-thread staging coordinates (chunk q = tid + i*256 -> row, swizzled col)
  int srow0 = tid >> 3, sc0 = ((tid & 7) ^ (srow0 & 7)) * 8;
  int srow1 = (tid + 256) >> 3, sc1 = ((tid & 7) ^ (srow1 & 7)) * 8;
  int dst0 = (wid * 64) * 8;            // wave-uniform LDS chunk base (ushort units)
  int dst1 = (wid * 64 + 256) * 8;

  short8 qf[4];
#pragma unroll
  for (int m = 0; m < 4; ++m)
    qf[m] = *(const short8*)(Qp + (size_t)qrow * DD + m * 16 + h * 8);

  // persistent zero vector: C-operand for first QK MFMA
  f32x16 zv;
#pragma unroll
  for (int r = 0; r < 16; ++r) zv[r] = 0.0f;

  f32x16 po[2];
  po[0] = zv; po[1] = zv;
  float mrun = -1e30f, lrun = 0.0f;

  // prologue: stage tile t0 into buffer 0 (async; drained by first barrier)
  {
    gload_lds16(Kp + (size_t)(t0 * 64 + srow0) * DD + sc0, &Ks[0][dst0]);
    gload_lds16(Vp + (size_t)srow0 * TT + t0 * 64 + sc0, &Vs[0][dst0]);
    gload_lds16(Kp + (size_t)(t0 * 64 + srow1) * DD + sc1, &Ks[0][dst1]);
    gload_lds16(Vp + (size_t)srow1 * TT + t0 * 64 + sc1, &Vs[0][dst1]);
  }

  int buf = 0;
  for (int t = t0; t < t1; ++t) {
    __syncthreads();                    // drains vmcnt: buf's K/V ready; prev reads done
    int kvb = t * 64;
    if (t + 1 < t1) {                   // async-stage next tile into other buffer
      int kvb2 = kvb + 64;
      gload_lds16(Kp + (size_t)(kvb2 + srow0) * DD + sc0, &Ks[buf ^ 1][dst0]);
      gload_lds16(Vp + (size_t)srow0 * TT + kvb2 + sc0, &Vs[buf ^ 1][dst0]);
      gload_lds16(Kp + (size_t)(kvb2 + srow1) * DD + sc1, &Ks[buf ^ 1][dst1]);
      gload_lds16(Vp + (size_t)srow1 * TT + kvb2 + sc1, &Vs[buf ^ 1][dst1]);
    }

    if (kvb <= q0 + 31) {               // wave-uniform visit test
      f32x16 st[2];
      __builtin_amdgcn_s_setprio(1);
#pragma unroll
      for (int t32 = 0; t32 < 2; ++t32) {
        int row = t32 * 32 + l31;
        {
          int off = row * 64 + ((h ^ (row & 7)) * 8);
          short8 kf = *(const short8*)(&Ks[buf][off]);
          st[t32] = __builtin_amdgcn_mfma_f32_32x32x16_bf16(kf, qf[0], zv, 0, 0, 0);
        }
#pragma unroll
        for (int m = 1; m < 4; ++m) {
          int off = row * 64 + (((2 * m + h) ^ (row & 7)) * 8);
          short8 kf = *(const short8*)(&Ks[buf][off]);
          st[t32] = __builtin_amdgcn_mfma_f32_32x32x16_bf16(kf, qf[m], st[t32], 0, 0, 0);
        }
      }
      __builtin_amdgcn_s_setprio(0);

      if (kvb + 63 > q0) {              // diagonal tiles: causal mask
#pragma unroll
        for (int t32 = 0; t32 < 2; ++t32)
#pragma unroll
          for (int r = 0; r < 16; ++r) {
            int kvg = kvb + t32 * 32 + (r & 3) + 8 * (r >> 2) + 4 * h;
            if (kvg > qrow) st[t32][r] = -1e30f;
          }
      }

      // row max: 4-chain v_max3 tree over 32 values, then cross-half
      float A = st[0][0], B = st[0][1], C = st[0][2], Dv = st[0][3];
#pragma unroll
      for (int r = 4; r < 16; r += 4) {
        A = fmax3(A, st[0][r], st[0][r + 1]);
        B = fmax3(B, st[0][r + 2], st[0][r + 3]);
        C = fmax3(C, st[1][r - 4], st[1][r - 3]);
        Dv = fmax3(Dv, st[1][r - 2], st[1][r - 1]);
      }
      C = fmax3(C, st[1][12], st[1][13]);
      Dv = fmax3(Dv, st[1][14], st[1][15]);
      float mx = fmaxf(fmax3(A, B, C), Dv);
      mx = fmaxf(mx, __shfl_xor(mx, 32));

      if (__any(mx - mrun > 8.0f)) {    // defer-max, log2 units
        float mnew = fmaxf(mrun, mx);
        float alpha = fexp2(mrun - mnew);
        lrun *= alpha;
#pragma unroll
        for (int dt = 0; dt < 2; ++dt)
#pragma unroll
          for (int r = 0; r < 16; ++r) po[dt][r] *= alpha;
        mrun = mnew;
      }

      float sum = 0.0f;
#pragma unroll
      for (int t32 = 0; t32 < 2; ++t32)
#pragma unroll
        for (int r = 0; r < 16; ++r) {
          float p = fexp2(st[t32][r] - mrun);
          st[t32][r] = p;
          sum += p;
        }
      sum += __shfl_xor(sum, 32);
      lrun += sum;

      // P -> bf16 B-fragments via cvt_pk + permlane32_swap
      short8 pf[4];
#pragma unroll
      for (int g = 0; g < 4; ++g) {
        int t32 = g >> 1, r0 = (g & 1) * 8;
        int a = cvtpk(st[t32][r0 + 0], st[t32][r0 + 1]);
        int b = cvtpk(st[t32][r0 + 4], st[t32][r0 + 5]);
        plswap(a, b);
        int c = cvtpk(st[t32][r0 + 2], st[t32][r0 + 3]);
        int d = cvtpk(st[t32][r0 + 6], st[t32][r0 + 7]);
        plswap(c, d);
        union { int w[4]; short8 s; } u;
        u.w[0] = a; u.w[1] = c; u.w[2] = b; u.w[3] = d;
        pf[g] = u.s;
      }

      // O^T += V^T · P
      __builtin_amdgcn_s_setprio(1);
#pragma unroll
      for (int dt = 0; dt < 2; ++dt) {
#pragma unroll
        for (int g = 0; g < 4; ++g) {
          int row = dt * 32 + l31;
          int off = row * 64 + (((2 * g + h) ^ (row & 7)) * 8);
          short8 vf = *(const short8*)(&Vs[buf][off]);
          po[dt] = __builtin_amdgcn_mfma_f32_32x32x16_bf16(vf, pf[g], po[dt], 0, 0, 0);
        }
      }
      __builtin_amdgcn_s_setprio(0);
    }

    buf ^= 1;
  }

  // store unnormalized partial O^T (bf16 pairs) + m,l
  int wrow = wid * 32 + l31;
  size_t pobase = (job * 128 + wrow) * 64;
#pragma unroll
  for (int dt = 0; dt < 2; ++dt)
#pragma unroll
    for (int r = 0; r < 16; r += 2) {
      int d = dt * 32 + (r & 3) + 8 * (r >> 2) + 4 * h;
      int w = cvtpk(po[dt][r], po[dt][r + 1]);
      *(int*)(PO + pobase + d) = w;
    }
  if (h == 0) {
    Pm[job * 128 + wrow] = mrun;
    Pl[job * 128 + wrow] = lrun;
  }
}

// ---------------- combine partials -> Yb bf16 (exp2 domain; no runtime-indexed reg arrays) ----------------
__global__ __launch_bounds__(256) void k_attn_combine(const unsigned short* __restrict__ PO,
                                                      const float* __restrict__ Pm,
                                                      const float* __restrict__ Pl,
                                                      unsigned short* __restrict__ Y) {
  int qt = blockIdx.x, bh = blockIdx.y;
  int nc = (2 * qt + 6) / 5;            // ceil(2(qt+1)/5), max 7
  size_t job0 = (size_t)bh * NJOBS + jbase(qt);
  int tid = threadIdx.x;
  int row = tid >> 1, half = tid & 1;

  float M = -1e30f;
  for (int c = 0; c < nc; ++c) M = fmaxf(M, Pm[(job0 + c) * 128 + row]);
  float L = 0.0f;
  for (int c = 0; c < nc; ++c)
    L += Pl[(job0 + c) * 128 + row] * fexp2(Pm[(job0 + c) * 128 + row] - M);
  float inv = 1.0f / L;

  float acc[32];
#pragma unroll
  for (int j = 0; j < 32; ++j) acc[j] = 0.0f;
  for (int c = 0; c < nc; ++c) {
    float wc = fexp2(Pm[(job0 + c) * 128 + row] - M);
    const unsigned short* p = PO + ((job0 + c) * 128 + row) * 64 + half * 32;
#pragma unroll
    for (int k = 0; k < 4; ++k) {
      short8 v = *(const short8*)(p + k * 8);
#pragma unroll
      for (int j = 0; j < 8; ++j) acc[k * 8 + j] += wc * bf2f((unsigned short)v[j]);
    }
  }
  int b = bh >> 4, hh = bh & 15;
  int t = qt * 128 + row;
  unsigned short* yp = Y + ((size_t)(b * TT + t)) * CCH + hh * DD + half * 32;
#pragma unroll
  for (int k = 0; k < 4; ++k) {
    short8 wv;
#pragma unroll
    for (int j = 0; j < 8; ++j) wv[j] = (short)f2bf(acc[k * 8 + j] * inv);
    *(short8*)(yp + k * 8) = wv;
  }
}

// ---------------- proj GEMM (m97 pattern): Yb bf16 @ Wt_proj bf16 + bias -> f32 out ----------------
__global__ __launch_bounds__(256) void k_proj_gemm(const unsigned short* __restrict__ Yb,
                                                   const unsigned short* __restrict__ Wt,
                                                   const float* __restrict__ bias,
                                                   float* __restrict__ Out) {
  __shared__ __align__(16) unsigned short As[128 * 32];
  __shared__ __align__(16) unsigned short Bs[128 * 32];
  int tid = threadIdx.x;
  int mb = blockIdx.x * 128;
  int nb = blockIdx.y * 128;
  int wid = tid >> 6, lane = tid & 63;
  int wr = (wid >> 1) * 64, wc = (wid & 1) * 64;
  int l15 = lane & 15, l4 = lane >> 4;
  int l16 = lane >> 2, lc = (lane & 3) * 8;
  f32x4 acc[4][4];
#pragma unroll
  for (int a = 0; a < 4; ++a)
#pragma unroll
    for (int b = 0; b < 4; ++b)
#pragma unroll
      for (int j = 0; j < 4; ++j) acc[a][b][j] = 0.0f;

  for (int kb = 0; kb < CCH; kb += 32) {
#pragma unroll
    for (int i = 0; i < 2; ++i) {
      int arow = wid * 32 + i * 16;
      gload_lds16(Yb + (size_t)(mb + arow + l16) * CCH + kb + lc, &As[arow * 32]);
      gload_lds16(Wt + (size_t)(nb + arow + l16) * CCH + kb + lc, &Bs[arow * 32]);
    }
    __syncthreads();
    short8 af[4], bfr[4];
#pragma unroll
    for (int mt = 0; mt < 4; ++mt) af[mt] = *(const short8*)(&As[(wr + mt * 16 + l15) * 32 + l4 * 8]);
#pragma unroll
    for (int nt = 0; nt < 4; ++nt) bfr[nt] = *(const short8*)(&Bs[(wc + nt * 16 + l15) * 32 + l4 * 8]);
#pragma unroll
    for (int mt = 0; mt < 4; ++mt)
#pragma unroll
      for (int nt = 0; nt < 4; ++nt)
        acc[mt][nt] = __builtin_amdgcn_mfma_f32_16x16x32_bf16(af[mt], bfr[nt], acc[mt][nt], 0, 0, 0);
    __syncthreads();
  }

#pragma unroll
  for (int mt = 0; mt < 4; ++mt) {
#pragma unroll
    for (int nt = 0; nt < 4; ++nt) {
      int gcol = nb + wc + nt * 16 + l15;
      float bv = bias[gcol];
#pragma unroll
      for (int j = 0; j < 4; ++j) {
        int grow = mb + wr + mt * 16 + l4 * 4 + j;
        Out[(size_t)grow * CCH + gcol] = acc[mt][nt][j] + bv;
      }
    }
  }
}

extern "C" void kernel_launch(void* const* d_in, const int* in_sizes, int n_in,
                              void* d_out, int out_size, void* d_ws, size_t ws_size,
                              hipStream_t stream) {
  const float* x      = (const float*)d_in[0];
  const float* W_qkv  = (const float*)d_in[1];
  const float* b_qkv  = (const float*)d_in[2];
  const float* W_proj = (const float*)d_in[3];
  const float* b_proj = (const float*)d_in[4];
  float* out = (float*)d_out;

  char* ws = (char*)d_ws;
  // PO (32MB) aliases [Wt_qkv | Xb]: both dead before k_attn writes PO (stream-ordered).
  size_t PO_BYTES = (size_t)32 * NJOBS * 128 * 64 * 2;            // 31.98 MB
  unsigned short* PO      = (unsigned short*)ws;
  unsigned short* Wt_qkv  = (unsigned short*)ws;                   // [0, 6.29MB)
  unsigned short* Xb      = (unsigned short*)(ws + (size_t)N3 * CCH * 2);  // [6.29, 14.68MB)
  size_t off = PO_BYTES;
  unsigned short* Wt_proj = (unsigned short*)(ws + off); off += (size_t)CCH * CCH * 2;  // 2.1 MB
  unsigned short* Qb      = (unsigned short*)(ws + off); off += (size_t)BT * CCH * 2;   // 8.4 MB
  unsigned short* Kb      = (unsigned short*)(ws + off); off += (size_t)BT * CCH * 2;   // 8.4 MB
  unsigned short* Vt      = (unsigned short*)(ws + off); off += (size_t)BT * CCH * 2;   // 8.4 MB
  unsigned short* Yb      = (unsigned short*)(ws + off); off += (size_t)BT * CCH * 2;   // 8.4 MB
  float*          Pm      = (float*)(ws + off);          off += (size_t)32 * NJOBS * 128 * 4;
  float*          Pl      = (float*)(ws + off);          off += (size_t)32 * NJOBS * 128 * 4;

  k_convert<<<dim3(BT * CCH / 8 / 256), 256, 0, stream>>>(x, Xb, BT * CCH / 8);
  k_transpose_cvt<<<dim3(N3 / 32, CCH / 32), 256, 0, stream>>>(W_qkv, Wt_qkv, CCH, N3);
  k_transpose_cvt<<<dim3(CCH / 32, CCH / 32), 256, 0, stream>>>(W_proj, Wt_proj, CCH, CCH);
  k_qkv_gemm<<<dim3(BT / 128, N3 / 128), 256, 0, stream>>>(Xb, Wt_qkv, b_qkv, Qb, Kb, Vt);
  k_attn<<<dim3(NJOBS, BB * HH), 256, 0, stream>>>(Qb, Kb, Vt, PO, Pm, Pl);
  k_attn_combine<<<dim3(TT / 128, BB * HH), 256, 0, stream>>>(PO, Pm, Pl, Yb);
  k_proj_gemm<<<dim3(BT / 128, CCH / 128), 256, 0, stream>>>(Yb, Wt_proj, b_proj, out);
}

// Round 9
// 129.664 us; speedup vs baseline: 1.3611x; 1.0176x over previous
//
#include <hip/hip_runtime.h>
#include <hip/hip_bf16.h>
#include <math.h>

#define BB 2
#define TT 2048
#define CCH 1024
#define HH 16
#define DD 64
#define BT (BB*TT)     // 4096
#define N3 (3*CCH)     // 3072

typedef __attribute__((ext_vector_type(8))) short short8;
typedef __attribute__((ext_vector_type(4))) float f32x4;
typedef __attribute__((ext_vector_type(16))) float f32x16;

__device__ __forceinline__ unsigned short f2bf(float f) {
  unsigned int u = __float_as_uint(f);
  unsigned int r = (u + 0x7FFFu + ((u >> 16) & 1u)) >> 16;  // RNE
  return (unsigned short)r;
}
__device__ __forceinline__ int cvtpk(float lo, float hi) {
  int r;
  asm("v_cvt_pk_bf16_f32 %0, %1, %2" : "=v"(r) : "v"(lo), "v"(hi));
  return r;
}
__device__ __forceinline__ void plswap(int &a, int &b) {
  asm("v_permlane32_swap_b32 %0, %1" : "+v"(a), "+v"(b));
}
__device__ __forceinline__ float fexp2(float x) {   // native v_exp_f32: 2^x, 1 inst
  float r;
  asm("v_exp_f32 %0, %1" : "=v"(r) : "v"(x));
  return r;
}
__device__ __forceinline__ void gload_lds16(const unsigned short* g, unsigned short* l) {
  __builtin_amdgcn_global_load_lds((const __attribute__((address_space(1))) void*)g,
                                   (__attribute__((address_space(3))) void*)l, 16, 0, 0);
}
__device__ __forceinline__ float fmax3(float a, float b, float c) {
  return fmaxf(fmaxf(a, b), c);   // fuses to v_max3_f32
}

// ---------------- f32 -> bf16 flat convert ----------------
__global__ __launch_bounds__(256) void k_convert(const float* __restrict__ in,
                                                 unsigned short* __restrict__ out, int n8) {
  int i = blockIdx.x * 256 + threadIdx.x;
  if (i < n8) {
    const float4 a = *(const float4*)(in + (size_t)i * 8);
    const float4 b = *(const float4*)(in + (size_t)i * 8 + 4);
    short8 v;
    v[0] = f2bf(a.x); v[1] = f2bf(a.y); v[2] = f2bf(a.z); v[3] = f2bf(a.w);
    v[4] = f2bf(b.x); v[5] = f2bf(b.y); v[6] = f2bf(b.z); v[7] = f2bf(b.w);
    *(short8*)(out + (size_t)i * 8) = v;
  }
}

// ---------------- transpose + f32->bf16 convert: out[c][r] = in[r][c] ----------------
__global__ __launch_bounds__(256) void k_transpose_cvt(const float* __restrict__ in,
                                                       unsigned short* __restrict__ out,
                                                       int R, int Cn) {
  __shared__ float tile[32][33];
  int tc = blockIdx.x * 32;
  int tr = blockIdx.y * 32;
  int lx = threadIdx.x & 31;
  int ly = threadIdx.x >> 5;  // 0..7
#pragma unroll
  for (int i = 0; i < 32; i += 8)
    tile[ly + i][lx] = in[(size_t)(tr + ly + i) * Cn + tc + lx];
  __syncthreads();
#pragma unroll
  for (int i = 0; i < 32; i += 8)
    out[(size_t)(tc + ly + i) * R + tr + lx] = f2bf(tile[lx][ly + i]);
}

// ---------------- QKV GEMM (m97 pattern): Xb bf16 @ Wt bf16 -> Q(scaled),K,Vt bf16 ----------------
__global__ __launch_bounds__(256) void k_qkv_gemm(const unsigned short* __restrict__ Xb,
                                                  const unsigned short* __restrict__ Wt,
                                                  const float* __restrict__ bias,
                                                  unsigned short* __restrict__ Qo,
                                                  unsigned short* __restrict__ Ko,
                                                  unsigned short* __restrict__ Vto) {
  __shared__ __align__(16) unsigned short As[128 * 32];
  __shared__ __align__(16) unsigned short Bs[128 * 32];
  int tid = threadIdx.x;
  int mb = blockIdx.x * 128;
  int nb = blockIdx.y * 128;
  int wid = tid >> 6, lane = tid & 63;
  int wr = (wid >> 1) * 64, wc = (wid & 1) * 64;
  int l15 = lane & 15, l4 = lane >> 4;
  int l16 = lane >> 2, lc = (lane & 3) * 8;   // staging row-within-16 / col
  f32x4 acc[4][4];
#pragma unroll
  for (int a = 0; a < 4; ++a)
#pragma unroll
    for (int b = 0; b < 4; ++b)
#pragma unroll
      for (int j = 0; j < 4; ++j) acc[a][b][j] = 0.0f;

  for (int kb = 0; kb < CCH; kb += 32) {
#pragma unroll
    for (int i = 0; i < 2; ++i) {
      int arow = wid * 32 + i * 16;
      gload_lds16(Xb + (size_t)(mb + arow + l16) * CCH + kb + lc, &As[arow * 32]);
      gload_lds16(Wt + (size_t)(nb + arow + l16) * CCH + kb + lc, &Bs[arow * 32]);
    }
    __syncthreads();
    short8 af[4], bfr[4];
#pragma unroll
    for (int mt = 0; mt < 4; ++mt) af[mt] = *(const short8*)(&As[(wr + mt * 16 + l15) * 32 + l4 * 8]);
#pragma unroll
    for (int nt = 0; nt < 4; ++nt) bfr[nt] = *(const short8*)(&Bs[(wc + nt * 16 + l15) * 32 + l4 * 8]);
#pragma unroll
    for (int mt = 0; mt < 4; ++mt)
#pragma unroll
      for (int nt = 0; nt < 4; ++nt)
        acc[mt][nt] = __builtin_amdgcn_mfma_f32_16x16x32_bf16(af[mt], bfr[nt], acc[mt][nt], 0, 0, 0);
    __syncthreads();
  }

#pragma unroll
  for (int mt = 0; mt < 4; ++mt) {
#pragma unroll
    for (int nt = 0; nt < 4; ++nt) {
      int gcol = nb + wc + nt * 16 + l15;        // 0..3071
      int which = gcol >> 10;
      int cc = gcol & 1023;
      int h = cc >> 6, d = cc & 63;
      float bv = bias[gcol];
#pragma unroll
      for (int j = 0; j < 4; ++j) {
        int grow = mb + wr + mt * 16 + l4 * 4 + j;  // 0..4095
        int b = grow >> 11, t = grow & 2047;
        float v = acc[mt][nt][j] + bv;
        size_t bh = (size_t)(b * HH + h);
        // fold sm_scale AND log2(e): softmax runs in exp2 domain
        if (which == 0)      Qo[(bh * TT + t) * DD + d] = f2bf(v * 0.18033688f);
        else if (which == 1) Ko[(bh * TT + t) * DD + d] = f2bf(v);
        else                 Vto[(bh * DD + d) * TT + t] = f2bf(v);
      }
    }
  }
}

// ---------------- causal flash attention: single-phase, balanced job mapping ----------------
// 1024 blocks of 128 threads (2 waves x 32 q-rows = 64-row q-subtile). Block i ->
// (u=i&255, k=i>>8): qsub complementary across k so every CU-slot u totals exactly
// 66 tile-visits. Writes normalized Yb directly -- no partials, no combine.
__global__ __launch_bounds__(128) void k_attn(const unsigned short* __restrict__ Qb,
                                              const unsigned short* __restrict__ Kb,
                                              const unsigned short* __restrict__ Vtb,
                                              unsigned short* __restrict__ Y) {
  __shared__ __align__(16) unsigned short Ks[2][64 * 64];   // [kv][d], swizzled 16B chunks
  __shared__ __align__(16) unsigned short Vs[2][64 * 64];   // [d][kv], swizzled 16B chunks
  int tid = threadIdx.x;            // 0..127
  int i = blockIdx.x;               // 0..1023
  int u = i & 255, k = i >> 8;
  int q8 = u >> 3;                  // 0..31
  int qsub;
  if (k == 0)      qsub = q8;
  else if (k == 1) qsub = 31 - q8;
  else if (k == 2) qsub = (q8 + 16) & 31;
  else             qsub = (15 - q8) & 31;
  int bh = (u & 7) + 8 * k;         // 0..31

  const unsigned short* Qp = Qb + (size_t)bh * TT * DD;
  const unsigned short* Kp = Kb + (size_t)bh * TT * DD;
  const unsigned short* Vp = Vtb + (size_t)bh * DD * TT;
  int wid = tid >> 6, lane = tid & 63;
  int l31 = lane & 31, h = lane >> 5;
  int q0 = qsub * 64 + wid * 32;
  int qrow = q0 + l31;

  short8 qf[4];
#pragma unroll
  for (int m = 0; m < 4; ++m)
    qf[m] = *(const short8*)(Qp + (size_t)qrow * DD + m * 16 + h * 8);

  f32x16 zv;
#pragma unroll
  for (int r = 0; r < 16; ++r) zv[r] = 0.0f;
  f32x16 po[2];
  po[0] = zv; po[1] = zv;
  float mrun = -1e30f, lrun = 0.0f;

  // stage tile 0 into buffer 0: 512 16B-chunks per operand, 4 per thread
#pragma unroll
  for (int i2 = 0; i2 < 4; ++i2) {
    int c = i2 * 128 + wid * 64 + lane;
    int srow = c >> 3, scol = ((c & 7) ^ (srow & 7)) * 8;
    int dst = (i2 * 128 + wid * 64) * 8;      // wave-uniform LDS base
    gload_lds16(Kp + (size_t)srow * DD + scol, &Ks[0][dst]);
    gload_lds16(Vp + (size_t)srow * TT + scol, &Vs[0][dst]);
  }

  int buf = 0;
  for (int t = 0; t <= qsub; ++t) {
    __syncthreads();                  // drains vmcnt: buf's K/V ready; prev reads done
    int kvb = t * 64;
    if (t < qsub) {                   // async-stage next tile into other buffer
      int kvb2 = kvb + 64;
#pragma unroll
      for (int i2 = 0; i2 < 4; ++i2) {
        int c = i2 * 128 + wid * 64 + lane;
        int srow = c >> 3, scol = ((c & 7) ^ (srow & 7)) * 8;
        int dst = (i2 * 128 + wid * 64) * 8;
        gload_lds16(Kp + (size_t)(kvb2 + srow) * DD + scol, &Ks[buf ^ 1][dst]);
        gload_lds16(Vp + (size_t)srow * TT + kvb2 + scol, &Vs[buf ^ 1][dst]);
      }
    }

    {
      f32x16 st[2];
      __builtin_amdgcn_s_setprio(1);
#pragma unroll
      for (int t32 = 0; t32 < 2; ++t32) {
        int row = t32 * 32 + l31;
        {
          int off = row * 64 + ((h ^ (row & 7)) * 8);
          short8 kf = *(const short8*)(&Ks[buf][off]);
          st[t32] = __builtin_amdgcn_mfma_f32_32x32x16_bf16(kf, qf[0], zv, 0, 0, 0);
        }
#pragma unroll
        for (int m = 1; m < 4; ++m) {
          int off = row * 64 + (((2 * m + h) ^ (row & 7)) * 8);
          short8 kf = *(const short8*)(&Ks[buf][off]);
          st[t32] = __builtin_amdgcn_mfma_f32_32x32x16_bf16(kf, qf[m], st[t32], 0, 0, 0);
        }
      }
      __builtin_amdgcn_s_setprio(0);

      if (kvb + 63 > q0) {            // diagonal tiles: causal mask
#pragma unroll
        for (int t32 = 0; t32 < 2; ++t32)
#pragma unroll
          for (int r = 0; r < 16; ++r) {
            int kvg = kvb + t32 * 32 + (r & 3) + 8 * (r >> 2) + 4 * h;
            if (kvg > qrow) st[t32][r] = -1e30f;
          }
      }

      // row max: v_max3 tree over 32 values, then cross-half
      float A = st[0][0], B = st[0][1], C = st[0][2], Dv = st[0][3];
#pragma unroll
      for (int r = 4; r < 16; r += 4) {
        A = fmax3(A, st[0][r], st[0][r + 1]);
        B = fmax3(B, st[0][r + 2], st[0][r + 3]);
        C = fmax3(C, st[1][r - 4], st[1][r - 3]);
        Dv = fmax3(Dv, st[1][r - 2], st[1][r - 1]);
      }
      C = fmax3(C, st[1][12], st[1][13]);
      Dv = fmax3(Dv, st[1][14], st[1][15]);
      float mx = fmaxf(fmax3(A, B, C), Dv);
      mx = fmaxf(mx, __shfl_xor(mx, 32));

      if (__any(mx - mrun > 8.0f)) {  // defer-max, log2 units
        float mnew = fmaxf(mrun, mx);
        float alpha = fexp2(mrun - mnew);
        lrun *= alpha;
#pragma unroll
        for (int dt = 0; dt < 2; ++dt)
#pragma unroll
          for (int r = 0; r < 16; ++r) po[dt][r] *= alpha;
        mrun = mnew;
      }

      float sum = 0.0f;
#pragma unroll
      for (int t32 = 0; t32 < 2; ++t32)
#pragma unroll
        for (int r = 0; r < 16; ++r) {
          float p = fexp2(st[t32][r] - mrun);
          st[t32][r] = p;
          sum += p;
        }
      sum += __shfl_xor(sum, 32);
      lrun += sum;

      // P -> bf16 B-fragments via cvt_pk + permlane32_swap
      short8 pf[4];
#pragma unroll
      for (int g = 0; g < 4; ++g) {
        int t32 = g >> 1, r0 = (g & 1) * 8;
        int a = cvtpk(st[t32][r0 + 0], st[t32][r0 + 1]);
        int b = cvtpk(st[t32][r0 + 4], st[t32][r0 + 5]);
        plswap(a, b);
        int c = cvtpk(st[t32][r0 + 2], st[t32][r0 + 3]);
        int d = cvtpk(st[t32][r0 + 6], st[t32][r0 + 7]);
        plswap(c, d);
        union { int w[4]; short8 s; } un;
        un.w[0] = a; un.w[1] = c; un.w[2] = b; un.w[3] = d;
        pf[g] = un.s;
      }

      // O^T += V^T . P
      __builtin_amdgcn_s_setprio(1);
#pragma unroll
      for (int dt = 0; dt < 2; ++dt) {
#pragma unroll
        for (int g = 0; g < 4; ++g) {
          int row = dt * 32 + l31;
          int off = row * 64 + (((2 * g + h) ^ (row & 7)) * 8);
          short8 vf = *(const short8*)(&Vs[buf][off]);
          po[dt] = __builtin_amdgcn_mfma_f32_32x32x16_bf16(vf, pf[g], po[dt], 0, 0, 0);
        }
      }
      __builtin_amdgcn_s_setprio(0);
    }

    buf ^= 1;
  }

  // normalize + write Yb directly
  float inv = 1.0f / lrun;
  int b = bh >> 4, hh = bh & 15;
  int trow = qsub * 64 + wid * 32 + l31;
  unsigned short* yp = Y + ((size_t)(b * TT + trow)) * CCH + hh * DD;
#pragma unroll
  for (int dt = 0; dt < 2; ++dt)
#pragma unroll
    for (int r = 0; r < 16; r += 2) {
      int d = dt * 32 + (r & 3) + 8 * (r >> 2) + 4 * h;
      *(int*)(yp + d) = cvtpk(po[dt][r] * inv, po[dt][r + 1] * inv);
    }
}

// ---------------- proj GEMM (m97 pattern): Yb bf16 @ Wt_proj bf16 + bias -> f32 out ----------------
__global__ __launch_bounds__(256) void k_proj_gemm(const unsigned short* __restrict__ Yb,
                                                   const unsigned short* __restrict__ Wt,
                                                   const float* __restrict__ bias,
                                                   float* __restrict__ Out) {
  __shared__ __align__(16) unsigned short As[128 * 32];
  __shared__ __align__(16) unsigned short Bs[128 * 32];
  int tid = threadIdx.x;
  int mb = blockIdx.x * 128;
  int nb = blockIdx.y * 128;
  int wid = tid >> 6, lane = tid & 63;
  int wr = (wid >> 1) * 64, wc = (wid & 1) * 64;
  int l15 = lane & 15, l4 = lane >> 4;
  int l16 = lane >> 2, lc = (lane & 3) * 8;
  f32x4 acc[4][4];
#pragma unroll
  for (int a = 0; a < 4; ++a)
#pragma unroll
    for (int b = 0; b < 4; ++b)
#pragma unroll
      for (int j = 0; j < 4; ++j) acc[a][b][j] = 0.0f;

  for (int kb = 0; kb < CCH; kb += 32) {
#pragma unroll
    for (int i = 0; i < 2; ++i) {
      int arow = wid * 32 + i * 16;
      gload_lds16(Yb + (size_t)(mb + arow + l16) * CCH + kb + lc, &As[arow * 32]);
      gload_lds16(Wt + (size_t)(nb + arow + l16) * CCH + kb + lc, &Bs[arow * 32]);
    }
    __syncthreads();
    short8 af[4], bfr[4];
#pragma unroll
    for (int mt = 0; mt < 4; ++mt) af[mt] = *(const short8*)(&As[(wr + mt * 16 + l15) * 32 + l4 * 8]);
#pragma unroll
    for (int nt = 0; nt < 4; ++nt) bfr[nt] = *(const short8*)(&Bs[(wc + nt * 16 + l15) * 32 + l4 * 8]);
#pragma unroll
    for (int mt = 0; mt < 4; ++mt)
#pragma unroll
      for (int nt = 0; nt < 4; ++nt)
        acc[mt][nt] = __builtin_amdgcn_mfma_f32_16x16x32_bf16(af[mt], bfr[nt], acc[mt][nt], 0, 0, 0);
    __syncthreads();
  }

#pragma unroll
  for (int mt = 0; mt < 4; ++mt) {
#pragma unroll
    for (int nt = 0; nt < 4; ++nt) {
      int gcol = nb + wc + nt * 16 + l15;
      float bv = bias[gcol];
#pragma unroll
      for (int j = 0; j < 4; ++j) {
        int grow = mb + wr + mt * 16 + l4 * 4 + j;
        Out[(size_t)grow * CCH + gcol] = acc[mt][nt][j] + bv;
      }
    }
  }
}

extern "C" void kernel_launch(void* const* d_in, const int* in_sizes, int n_in,
                              void* d_out, int out_size, void* d_ws, size_t ws_size,
                              hipStream_t stream) {
  const float* x      = (const float*)d_in[0];
  const float* W_qkv  = (const float*)d_in[1];
  const float* b_qkv  = (const float*)d_in[2];
  const float* W_proj = (const float*)d_in[3];
  const float* b_proj = (const float*)d_in[4];
  float* out = (float*)d_out;

  char* ws = (char*)d_ws;
  size_t off = 0;
  unsigned short* Wt_qkv  = (unsigned short*)(ws + off); off += (size_t)N3 * CCH * 2;   // 6.3 MB
  unsigned short* Wt_proj = (unsigned short*)(ws + off); off += (size_t)CCH * CCH * 2;  // 2.1 MB
  unsigned short* Xb      = (unsigned short*)(ws + off); off += (size_t)BT * CCH * 2;   // 8.4 MB
  unsigned short* Qb      = (unsigned short*)(ws + off); off += (size_t)BT * CCH * 2;   // 8.4 MB
  unsigned short* Kb      = (unsigned short*)(ws + off); off += (size_t)BT * CCH * 2;   // 8.4 MB
  unsigned short* Vt      = (unsigned short*)(ws + off); off += (size_t)BT * CCH * 2;   // 8.4 MB
  unsigned short* Yb      = (unsigned short*)(ws + off); off += (size_t)BT * CCH * 2;   // 8.4 MB

  k_convert<<<dim3(BT * CCH / 8 / 256), 256, 0, stream>>>(x, Xb, BT * CCH / 8);
  k_transpose_cvt<<<dim3(N3 / 32, CCH / 32), 256, 0, stream>>>(W_qkv, Wt_qkv, CCH, N3);
  k_transpose_cvt<<<dim3(CCH / 32, CCH / 32), 256, 0, stream>>>(W_proj, Wt_proj, CCH, CCH);
  k_qkv_gemm<<<dim3(BT / 128, N3 / 128), 256, 0, stream>>>(Xb, Wt_qkv, b_qkv, Qb, Kb, Vt);
  k_attn<<<dim3(1024), 128, 0, stream>>>(Qb, Kb, Vt, Yb);
  k_proj_gemm<<<dim3(BT / 128, CCH / 128), 256, 0, stream>>>(Yb, Wt_proj, b_proj, out);
}

// Round 10
// 125.876 us; speedup vs baseline: 1.4021x; 1.0301x over previous
//
#include <hip/hip_runtime.h>
#include <hip/hip_bf16.h>
#include <math.h>

#define BB 2
#define TT 2048
#define CCH 1024
#define HH 16
#define DD 64
#define BT (BB*TT)     // 4096
#define N3 (3*CCH)     // 3072

typedef __attribute__((ext_vector_type(8))) short short8;
typedef __attribute__((ext_vector_type(4))) float f32x4;
typedef __attribute__((ext_vector_type(16))) float f32x16;

__device__ __forceinline__ unsigned short f2bf(float f) {
  unsigned int u = __float_as_uint(f);
  unsigned int r = (u + 0x7FFFu + ((u >> 16) & 1u)) >> 16;  // RNE
  return (unsigned short)r;
}
__device__ __forceinline__ int cvtpk(float lo, float hi) {
  int r;
  asm("v_cvt_pk_bf16_f32 %0, %1, %2" : "=v"(r) : "v"(lo), "v"(hi));
  return r;
}
__device__ __forceinline__ void plswap(int &a, int &b) {
  asm("v_permlane32_swap_b32 %0, %1" : "+v"(a), "+v"(b));
}
__device__ __forceinline__ float fexp2(float x) {   // native v_exp_f32: 2^x, 1 inst
  float r;
  asm("v_exp_f32 %0, %1" : "=v"(r) : "v"(x));
  return r;
}
__device__ __forceinline__ void gload_lds16(const unsigned short* g, unsigned short* l) {
  __builtin_amdgcn_global_load_lds((const __attribute__((address_space(1))) void*)g,
                                   (__attribute__((address_space(3))) void*)l, 16, 0, 0);
}
__device__ __forceinline__ float fmax3(float a, float b, float c) {
  return fmaxf(fmaxf(a, b), c);   // fuses to v_max3_f32
}

// ---------------- f32 -> bf16 flat convert ----------------
__global__ __launch_bounds__(256) void k_convert(const float* __restrict__ in,
                                                 unsigned short* __restrict__ out, int n8) {
  int i = blockIdx.x * 256 + threadIdx.x;
  if (i < n8) {
    const float4 a = *(const float4*)(in + (size_t)i * 8);
    const float4 b = *(const float4*)(in + (size_t)i * 8 + 4);
    short8 v;
    v[0] = f2bf(a.x); v[1] = f2bf(a.y); v[2] = f2bf(a.z); v[3] = f2bf(a.w);
    v[4] = f2bf(b.x); v[5] = f2bf(b.y); v[6] = f2bf(b.z); v[7] = f2bf(b.w);
    *(short8*)(out + (size_t)i * 8) = v;
  }
}

// ---------------- transpose + f32->bf16 convert: out[c][r] = in[r][c] ----------------
__global__ __launch_bounds__(256) void k_transpose_cvt(const float* __restrict__ in,
                                                       unsigned short* __restrict__ out,
                                                       int R, int Cn) {
  __shared__ float tile[32][33];
  int tc = blockIdx.x * 32;
  int tr = blockIdx.y * 32;
  int lx = threadIdx.x & 31;
  int ly = threadIdx.x >> 5;  // 0..7
#pragma unroll
  for (int i = 0; i < 32; i += 8)
    tile[ly + i][lx] = in[(size_t)(tr + ly + i) * Cn + tc + lx];
  __syncthreads();
#pragma unroll
  for (int i = 0; i < 32; i += 8)
    out[(size_t)(tc + ly + i) * R + tr + lx] = f2bf(tile[lx][ly + i]);
}

// ---------------- QKV GEMM (m97 pattern): Xb bf16 @ Wt bf16 -> Q(scaled),K,Vt bf16 ----------------
__global__ __launch_bounds__(256) void k_qkv_gemm(const unsigned short* __restrict__ Xb,
                                                  const unsigned short* __restrict__ Wt,
                                                  const float* __restrict__ bias,
                                                  unsigned short* __restrict__ Qo,
                                                  unsigned short* __restrict__ Ko,
                                                  unsigned short* __restrict__ Vto) {
  __shared__ __align__(16) unsigned short As[128 * 32];
  __shared__ __align__(16) unsigned short Bs[128 * 32];
  int tid = threadIdx.x;
  int mb = blockIdx.x * 128;
  int nb = blockIdx.y * 128;
  int wid = tid >> 6, lane = tid & 63;
  int wr = (wid >> 1) * 64, wc = (wid & 1) * 64;
  int l15 = lane & 15, l4 = lane >> 4;
  int l16 = lane >> 2, lc = (lane & 3) * 8;   // staging row-within-16 / col
  f32x4 acc[4][4];
#pragma unroll
  for (int a = 0; a < 4; ++a)
#pragma unroll
    for (int b = 0; b < 4; ++b)
#pragma unroll
      for (int j = 0; j < 4; ++j) acc[a][b][j] = 0.0f;

  for (int kb = 0; kb < CCH; kb += 32) {
#pragma unroll
    for (int i = 0; i < 2; ++i) {
      int arow = wid * 32 + i * 16;
      gload_lds16(Xb + (size_t)(mb + arow + l16) * CCH + kb + lc, &As[arow * 32]);
      gload_lds16(Wt + (size_t)(nb + arow + l16) * CCH + kb + lc, &Bs[arow * 32]);
    }
    __syncthreads();
    short8 af[4], bfr[4];
#pragma unroll
    for (int mt = 0; mt < 4; ++mt) af[mt] = *(const short8*)(&As[(wr + mt * 16 + l15) * 32 + l4 * 8]);
#pragma unroll
    for (int nt = 0; nt < 4; ++nt) bfr[nt] = *(const short8*)(&Bs[(wc + nt * 16 + l15) * 32 + l4 * 8]);
#pragma unroll
    for (int mt = 0; mt < 4; ++mt)
#pragma unroll
      for (int nt = 0; nt < 4; ++nt)
        acc[mt][nt] = __builtin_amdgcn_mfma_f32_16x16x32_bf16(af[mt], bfr[nt], acc[mt][nt], 0, 0, 0);
    __syncthreads();
  }

#pragma unroll
  for (int mt = 0; mt < 4; ++mt) {
#pragma unroll
    for (int nt = 0; nt < 4; ++nt) {
      int gcol = nb + wc + nt * 16 + l15;        // 0..3071
      int which = gcol >> 10;
      int cc = gcol & 1023;
      int h = cc >> 6, d = cc & 63;
      float bv = bias[gcol];
#pragma unroll
      for (int j = 0; j < 4; ++j) {
        int grow = mb + wr + mt * 16 + l4 * 4 + j;  // 0..4095
        int b = grow >> 11, t = grow & 2047;
        float v = acc[mt][nt][j] + bv;
        size_t bh = (size_t)(b * HH + h);
        // fold sm_scale AND log2(e): softmax runs in exp2 domain
        if (which == 0)      Qo[(bh * TT + t) * DD + d] = f2bf(v * 0.18033688f);
        else if (which == 1) Ko[(bh * TT + t) * DD + d] = f2bf(v);
        else                 Vto[(bh * DD + d) * TT + t] = f2bf(v);
      }
    }
  }
}

// ---------------- causal flash attention: single-phase, descending-size dispatch ----------------
// 1024 blocks of 128 threads (2 waves x 32 q-rows = 64-row q-subtile). Jobs ordered
// biggest-first (qsub = 31 - jx>>5): oversubscription (4-5 resident of 1024) + backfill
// balances CUs without assuming blockIdx->CU mapping. Writes normalized Yb directly.
__global__ __launch_bounds__(128) void k_attn(const unsigned short* __restrict__ Qb,
                                              const unsigned short* __restrict__ Kb,
                                              const unsigned short* __restrict__ Vtb,
                                              unsigned short* __restrict__ Y) {
  __shared__ __align__(16) unsigned short Ks[2][64 * 64];   // [kv][d], swizzled 16B chunks
  __shared__ __align__(16) unsigned short Vs[2][64 * 64];   // [d][kv], swizzled 16B chunks
  int tid = threadIdx.x;            // 0..127
  int jx = blockIdx.x;              // 0..1023
  int qsub = 31 - (jx >> 5);        // biggest jobs (32 tile-visits) dispatch first
  int bh = jx & 31;

  const unsigned short* Qp = Qb + (size_t)bh * TT * DD;
  const unsigned short* Kp = Kb + (size_t)bh * TT * DD;
  const unsigned short* Vp = Vtb + (size_t)bh * DD * TT;
  int wid = tid >> 6, lane = tid & 63;
  int l31 = lane & 31, h = lane >> 5;
  int q0 = qsub * 64 + wid * 32;
  int qrow = q0 + l31;

  short8 qf[4];
#pragma unroll
  for (int m = 0; m < 4; ++m)
    qf[m] = *(const short8*)(Qp + (size_t)qrow * DD + m * 16 + h * 8);

  f32x16 zv;
#pragma unroll
  for (int r = 0; r < 16; ++r) zv[r] = 0.0f;
  f32x16 po[2];
  po[0] = zv; po[1] = zv;
  float mrun = -1e30f, lrun = 0.0f;

  // stage tile 0 into buffer 0: 512 16B-chunks per operand, 4 per thread
#pragma unroll
  for (int i2 = 0; i2 < 4; ++i2) {
    int c = i2 * 128 + wid * 64 + lane;
    int srow = c >> 3, scol = ((c & 7) ^ (srow & 7)) * 8;
    int dst = (i2 * 128 + wid * 64) * 8;      // wave-uniform LDS base
    gload_lds16(Kp + (size_t)srow * DD + scol, &Ks[0][dst]);
    gload_lds16(Vp + (size_t)srow * TT + scol, &Vs[0][dst]);
  }

  int buf = 0;
  for (int t = 0; t <= qsub; ++t) {
    __syncthreads();                  // drains vmcnt: buf's K/V ready; prev reads done
    int kvb = t * 64;
    if (t < qsub) {                   // async-stage next tile into other buffer
      int kvb2 = kvb + 64;
#pragma unroll
      for (int i2 = 0; i2 < 4; ++i2) {
        int c = i2 * 128 + wid * 64 + lane;
        int srow = c >> 3, scol = ((c & 7) ^ (srow & 7)) * 8;
        int dst = (i2 * 128 + wid * 64) * 8;
        gload_lds16(Kp + (size_t)(kvb2 + srow) * DD + scol, &Ks[buf ^ 1][dst]);
        gload_lds16(Vp + (size_t)srow * TT + kvb2 + scol, &Vs[buf ^ 1][dst]);
      }
    }

    {
      f32x16 st[2];
      __builtin_amdgcn_s_setprio(1);
#pragma unroll
      for (int t32 = 0; t32 < 2; ++t32) {
        int row = t32 * 32 + l31;
        {
          int off = row * 64 + ((h ^ (row & 7)) * 8);
          short8 kf = *(const short8*)(&Ks[buf][off]);
          st[t32] = __builtin_amdgcn_mfma_f32_32x32x16_bf16(kf, qf[0], zv, 0, 0, 0);
        }
#pragma unroll
        for (int m = 1; m < 4; ++m) {
          int off = row * 64 + (((2 * m + h) ^ (row & 7)) * 8);
          short8 kf = *(const short8*)(&Ks[buf][off]);
          st[t32] = __builtin_amdgcn_mfma_f32_32x32x16_bf16(kf, qf[m], st[t32], 0, 0, 0);
        }
      }
      __builtin_amdgcn_s_setprio(0);

      if (kvb + 63 > q0) {            // diagonal tiles: causal mask
#pragma unroll
        for (int t32 = 0; t32 < 2; ++t32)
#pragma unroll
          for (int r = 0; r < 16; ++r) {
            int kvg = kvb + t32 * 32 + (r & 3) + 8 * (r >> 2) + 4 * h;
            if (kvg > qrow) st[t32][r] = -1e30f;
          }
      }

      // row max: v_max3 tree over 32 values, then cross-half
      float A = st[0][0], B = st[0][1], C = st[0][2], Dv = st[0][3];
#pragma unroll
      for (int r = 4; r < 16; r += 4) {
        A = fmax3(A, st[0][r], st[0][r + 1]);
        B = fmax3(B, st[0][r + 2], st[0][r + 3]);
        C = fmax3(C, st[1][r - 4], st[1][r - 3]);
        Dv = fmax3(Dv, st[1][r - 2], st[1][r - 1]);
      }
      C = fmax3(C, st[1][12], st[1][13]);
      Dv = fmax3(Dv, st[1][14], st[1][15]);
      float mx = fmaxf(fmax3(A, B, C), Dv);
      mx = fmaxf(mx, __shfl_xor(mx, 32));

      if (__any(mx - mrun > 8.0f)) {  // defer-max, log2 units
        float mnew = fmaxf(mrun, mx);
        float alpha = fexp2(mrun - mnew);
        lrun *= alpha;
#pragma unroll
        for (int dt = 0; dt < 2; ++dt)
#pragma unroll
          for (int r = 0; r < 16; ++r) po[dt][r] *= alpha;
        mrun = mnew;
      }

      float sum = 0.0f;
#pragma unroll
      for (int t32 = 0; t32 < 2; ++t32)
#pragma unroll
        for (int r = 0; r < 16; ++r) {
          float p = fexp2(st[t32][r] - mrun);
          st[t32][r] = p;
          sum += p;
        }
      sum += __shfl_xor(sum, 32);
      lrun += sum;

      // P -> bf16 B-fragments via cvt_pk + permlane32_swap
      short8 pf[4];
#pragma unroll
      for (int g = 0; g < 4; ++g) {
        int t32 = g >> 1, r0 = (g & 1) * 8;
        int a = cvtpk(st[t32][r0 + 0], st[t32][r0 + 1]);
        int b = cvtpk(st[t32][r0 + 4], st[t32][r0 + 5]);
        plswap(a, b);
        int c = cvtpk(st[t32][r0 + 2], st[t32][r0 + 3]);
        int d = cvtpk(st[t32][r0 + 6], st[t32][r0 + 7]);
        plswap(c, d);
        union { int w[4]; short8 s; } un;
        un.w[0] = a; un.w[1] = c; un.w[2] = b; un.w[3] = d;
        pf[g] = un.s;
      }

      // O^T += V^T . P
      __builtin_amdgcn_s_setprio(1);
#pragma unroll
      for (int dt = 0; dt < 2; ++dt) {
#pragma unroll
        for (int g = 0; g < 4; ++g) {
          int row = dt * 32 + l31;
          int off = row * 64 + (((2 * g + h) ^ (row & 7)) * 8);
          short8 vf = *(const short8*)(&Vs[buf][off]);
          po[dt] = __builtin_amdgcn_mfma_f32_32x32x16_bf16(vf, pf[g], po[dt], 0, 0, 0);
        }
      }
      __builtin_amdgcn_s_setprio(0);
    }

    buf ^= 1;
  }

  // normalize + write Yb directly
  float inv = 1.0f / lrun;
  int b = bh >> 4, hh = bh & 15;
  int trow = qsub * 64 + wid * 32 + l31;
  unsigned short* yp = Y + ((size_t)(b * TT + trow)) * CCH + hh * DD;
#pragma unroll
  for (int dt = 0; dt < 2; ++dt)
#pragma unroll
    for (int r = 0; r < 16; r += 2) {
      int d = dt * 32 + (r & 3) + 8 * (r >> 2) + 4 * h;
      *(int*)(yp + d) = cvtpk(po[dt][r] * inv, po[dt][r + 1] * inv);
    }
}

// ---------------- proj GEMM (m97 pattern): Yb bf16 @ Wt_proj bf16 + bias -> f32 out ----------------
__global__ __launch_bounds__(256) void k_proj_gemm(const unsigned short* __restrict__ Yb,
                                                   const unsigned short* __restrict__ Wt,
                                                   const float* __restrict__ bias,
                                                   float* __restrict__ Out) {
  __shared__ __align__(16) unsigned short As[128 * 32];
  __shared__ __align__(16) unsigned short Bs[128 * 32];
  int tid = threadIdx.x;
  int mb = blockIdx.x * 128;
  int nb = blockIdx.y * 128;
  int wid = tid >> 6, lane = tid & 63;
  int wr = (wid >> 1) * 64, wc = (wid & 1) * 64;
  int l15 = lane & 15, l4 = lane >> 4;
  int l16 = lane >> 2, lc = (lane & 3) * 8;
  f32x4 acc[4][4];
#pragma unroll
  for (int a = 0; a < 4; ++a)
#pragma unroll
    for (int b = 0; b < 4; ++b)
#pragma unroll
      for (int j = 0; j < 4; ++j) acc[a][b][j] = 0.0f;

  for (int kb = 0; kb < CCH; kb += 32) {
#pragma unroll
    for (int i = 0; i < 2; ++i) {
      int arow = wid * 32 + i * 16;
      gload_lds16(Yb + (size_t)(mb + arow + l16) * CCH + kb + lc, &As[arow * 32]);
      gload_lds16(Wt + (size_t)(nb + arow + l16) * CCH + kb + lc, &Bs[arow * 32]);
    }
    __syncthreads();
    short8 af[4], bfr[4];
#pragma unroll
    for (int mt = 0; mt < 4; ++mt) af[mt] = *(const short8*)(&As[(wr + mt * 16 + l15) * 32 + l4 * 8]);
#pragma unroll
    for (int nt = 0; nt < 4; ++nt) bfr[nt] = *(const short8*)(&Bs[(wc + nt * 16 + l15) * 32 + l4 * 8]);
#pragma unroll
    for (int mt = 0; mt < 4; ++mt)
#pragma unroll
      for (int nt = 0; nt < 4; ++nt)
        acc[mt][nt] = __builtin_amdgcn_mfma_f32_16x16x32_bf16(af[mt], bfr[nt], acc[mt][nt], 0, 0, 0);
    __syncthreads();
  }

#pragma unroll
  for (int mt = 0; mt < 4; ++mt) {
#pragma unroll
    for (int nt = 0; nt < 4; ++nt) {
      int gcol = nb + wc + nt * 16 + l15;
      float bv = bias[gcol];
#pragma unroll
      for (int j = 0; j < 4; ++j) {
        int grow = mb + wr + mt * 16 + l4 * 4 + j;
        Out[(size_t)grow * CCH + gcol] = acc[mt][nt][j] + bv;
      }
    }
  }
}

extern "C" void kernel_launch(void* const* d_in, const int* in_sizes, int n_in,
                              void* d_out, int out_size, void* d_ws, size_t ws_size,
                              hipStream_t stream) {
  const float* x      = (const float*)d_in[0];
  const float* W_qkv  = (const float*)d_in[1];
  const float* b_qkv  = (const float*)d_in[2];
  const float* W_proj = (const float*)d_in[3];
  const float* b_proj = (const float*)d_in[4];
  float* out = (float*)d_out;

  char* ws = (char*)d_ws;
  size_t off = 0;
  unsigned short* Wt_qkv  = (unsigned short*)(ws + off); off += (size_t)N3 * CCH * 2;   // 6.3 MB
  unsigned short* Wt_proj = (unsigned short*)(ws + off); off += (size_t)CCH * CCH * 2;  // 2.1 MB
  unsigned short* Xb      = (unsigned short*)(ws + off); off += (size_t)BT * CCH * 2;   // 8.4 MB
  unsigned short* Qb      = (unsigned short*)(ws + off); off += (size_t)BT * CCH * 2;   // 8.4 MB
  unsigned short* Kb      = (unsigned short*)(ws + off); off += (size_t)BT * CCH * 2;   // 8.4 MB
  unsigned short* Vt      = (unsigned short*)(ws + off); off += (size_t)BT * CCH * 2;   // 8.4 MB
  unsigned short* Yb      = (unsigned short*)(ws + off); off += (size_t)BT * CCH * 2;   // 8.4 MB

  k_convert<<<dim3(BT * CCH / 8 / 256), 256, 0, stream>>>(x, Xb, BT * CCH / 8);
  k_transpose_cvt<<<dim3(N3 / 32, CCH / 32), 256, 0, stream>>>(W_qkv, Wt_qkv, CCH, N3);
  k_transpose_cvt<<<dim3(CCH / 32, CCH / 32), 256, 0, stream>>>(W_proj, Wt_proj, CCH, CCH);
  k_qkv_gemm<<<dim3(BT / 128, N3 / 128), 256, 0, stream>>>(Xb, Wt_qkv, b_qkv, Qb, Kb, Vt);
  k_attn<<<dim3(1024), 128, 0, stream>>>(Qb, Kb, Vt, Yb);
  k_proj_gemm<<<dim3(BT / 128, CCH / 128), 256, 0, stream>>>(Yb, Wt_proj, b_proj, out);
}